// Round 16
// baseline (259.565 us; speedup 1.0000x reference)
//
#include <hip/hip_runtime.h>
#include <hip/hip_bf16.h>

// ---------------- problem constants ----------------
// x: [B=8, N1=4, S=64, L=8192], PATCH=128 -> Lp=64, P=128, F=256, Lout=62
// out: [8,4,64,62,1] fp32

typedef _Float16 fp16_t;
typedef _Float16 fp16x8 __attribute__((ext_vector_type(8)));
typedef __fp16 pkh2 __attribute__((ext_vector_type(2)));   // cvt_pkrtz result type
typedef float f32x4 __attribute__((ext_vector_type(4)));

// ws float-word offsets
constexpr int WOFF_CNT   = 0;     // 16 uints
constexpr int WOFF_CONST = 32;    // 1 float
constexpr int WOFF_VF    = 64;    // 256 floats
constexpr int WOFF_VB    = 320;   // 256 floats
constexpr int WOFF_W1T   = 1024;                // f16 [2][4][256][32]
constexpr int WOFF_CWT   = WOFF_W1T + 32768;    // f16 [2][24][256][32]

// silu via v_rcp (1 ulp): R13 PMC confirmed VALUBusy 52% -> 27% vs IEEE divide.
__device__ __forceinline__ float silu_f(float v) {
    return v * __builtin_amdgcn_rcpf(1.0f + __expf(-v));
}

// ---------------- prep (512 thr): rowcount (512 blocks) + weight pack ----------
// bid <512   : raw-space corr counting for (b = bid>>6, s = bid&63), 8-way split
// bid 512-559: conv-weight slice pack
// bid 560-567: W1 slice pack
// bid 568-575: v = W2@Wr (bid 568 tid 0 also writes const term)
__global__ __launch_bounds__(512) void prep_kernel(
    const float* __restrict__ c,
    const float* __restrict__ W2f, const float* __restrict__ b2f,
    const float* __restrict__ W2b, const float* __restrict__ b2b,
    const float* __restrict__ Wr,  const float* __restrict__ br,
    const float* __restrict__ W1f, const float* __restrict__ W1b,
    const float* __restrict__ Cwf, const float* __restrict__ Cwb,
    float* __restrict__ wsf) {
    const int bid = blockIdx.x;
    const int tid = threadIdx.x;

    if (bid < 512) {
        // ---- rowcount: corr_st > thr  <=>  dot - N*ms*mt > thr*N*ss*st ----
        const int b = bid >> 6, s = bid & 63;
        unsigned int* cnts = (unsigned int*)wsf + WOFF_CNT;
        const float* cb = c + (size_t)b * 65536;

        __shared__ __align__(16) float rowv[1024];
        __shared__ float ms_sh, ss_sh;
        if (tid < 256) *(float4*)&rowv[tid * 4] = *(const float4*)&cb[s * 1024 + tid * 4];
        __syncthreads();

        const int t = tid >> 3, part = tid & 7;   // 64 t-rows x 8 parts of 128 cols
        const float4* src  = (const float4*)(cb + t * 1024 + part * 128);
        const float4* mine = (const float4*)(rowv + part * 128);
        float dot = 0.0f, sum = 0.0f, sq = 0.0f;
        #pragma unroll 8
        for (int i = 0; i < 32; ++i) {
            float4 a = mine[i];
            float4 bb = src[i];
            dot += a.x * bb.x + a.y * bb.y + a.z * bb.z + a.w * bb.w;
            sum += bb.x + bb.y + bb.z + bb.w;
            sq  += bb.x * bb.x + bb.y * bb.y + bb.z * bb.z + bb.w * bb.w;
        }
        dot += __shfl_down(dot, 4); dot += __shfl_down(dot, 2); dot += __shfl_down(dot, 1);
        sum += __shfl_down(sum, 4); sum += __shfl_down(sum, 2); sum += __shfl_down(sum, 1);
        sq  += __shfl_down(sq, 4);  sq  += __shfl_down(sq, 2);  sq  += __shfl_down(sq, 1);

        float mt = 0.0f, st = 0.0f;
        if (part == 0) {
            mt = sum * (1.0f / 1024.0f);
            st = sqrtf(fmaxf((sq - 1024.0f * mt * mt) * (1.0f / 1023.0f), 0.0f));
            if (t == s) { ms_sh = mt; ss_sh = st; }
        }
        __syncthreads();
        const float ms = ms_sh, ss = ss_sh;

        const bool valid = (part == 0) && (t != s);
        const float ctr = dot - 1024.0f * ms * mt;               // 1024*cov
        unsigned long long mthr = __ballot(valid && (ctr > 0.6f * 1024.0f * ss * st));
        unsigned long long mpos = __ballot(valid && (ctr > 0.0f));
        if ((tid & 63) == 0) {
            atomicAdd(&cnts[b],     (unsigned int)__popcll(mthr));
            atomicAdd(&cnts[8 + b], (unsigned int)__popcll(mpos));
        }
    } else if (bid < 560) {
        const int idx = bid - 512;
        const int d = idx / 24, ks = idx % 24;
        const float* Cw = d ? Cwb : Cwf;
        fp16_t* cwt = (fp16_t*)(wsf + WOFF_CWT) + d * 196608;
        const int base = ks * 32;
        const int k = base >> 8, i0 = base & 255;
        const int o = tid >> 1, jh = (tid & 1) * 2;
        fp16x8 v[2];
        #pragma unroll
        for (int jj = 0; jj < 2; ++jj)
            #pragma unroll
            for (int e = 0; e < 8; ++e)
                v[jj][e] = (fp16_t)Cw[(o * 256 + i0 + (jh + jj) * 8 + e) * 3 + k];
        fp16x8* dst = (fp16x8*)(cwt + (ks * 256 + o) * 32 + jh * 8);
        dst[0] = v[0]; dst[1] = v[1];
    } else if (bid < 568) {
        const int sl = bid - 560;
        const int d = sl >> 2, ks = sl & 3;
        const float* W1 = d ? W1b : W1f;
        fp16_t* w1t = (fp16_t*)(wsf + WOFF_W1T) + d * 32768;
        const int o = tid >> 1, jh = (tid & 1) * 2;
        fp16x8 v[2];
        #pragma unroll
        for (int jj = 0; jj < 2; ++jj)
            #pragma unroll
            for (int e = 0; e < 8; ++e)
                v[jj][e] = (fp16_t)W1[(ks * 32 + (jh + jj) * 8 + e) * 256 + o];
        fp16x8* dst = (fp16x8*)(w1t + (ks * 256 + o) * 32 + jh * 8);
        dst[0] = v[0]; dst[1] = v[1];
    } else {
        const int vb = bid - 568;
        const int d = vb >> 2, q = vb & 3;
        const int w = tid >> 6, lane = tid & 63;   // 8 waves x 8 rows
        const float* W2 = d ? W2b : W2f;
        float4 wr4 = ((const float4*)Wr)[lane];
        for (int it = 0; it < 8; ++it) {
            int row = q * 64 + w * 8 + it;
            float4 a = ((const float4*)(W2 + row * 256))[lane];
            float p = a.x * wr4.x + a.y * wr4.y + a.z * wr4.z + a.w * wr4.w;
            #pragma unroll
            for (int off = 32; off > 0; off >>= 1) p += __shfl_down(p, off);
            if (lane == 0) wsf[(d ? WOFF_VB : WOFF_VF) + row] = p;
        }
        if (bid == 568 && tid == 0) {
            float cc = 0.0f;
            for (int g = 0; g < 256; ++g) cc += (b2f[g] + b2b[g]) * Wr[g];
            wsf[WOFF_CONST] = cc + br[0];
        }
    }
}

// ---------------- fused main: one (b,n,s,dir) per block (R15 core) --------------
// grid 4096: dir = mb&1, s = (mb>>1)&63, bn = mb>>7. 4 waves; wave w owns cols
// [64w, 64w+64). M=64. LDS = EXACTLY 32768 B -> 5 blocks/CU (163840 = 160 KiB).
// Pad rows 64/65 dropped: conv reads them OOB/garbage, but they only feed output
// rows 62/63 which are never stored (out writes tid<62). red aliases hb (dead
// after conv), re-zeroed between two barriers before the epilogue.
__global__ __launch_bounds__(256, 4) void fused_main(
    const float* __restrict__ x,
    const float* __restrict__ b1f, const float* __restrict__ Cbf,
    const float* __restrict__ b1b, const float* __restrict__ Cbb,
    const float* __restrict__ wsf,
    float* __restrict__ out) {
    __shared__ __align__(16) char hb[64 * 512];   // 32768 B, rows XOR-swizzled
    float* red = (float*)hb;                      // aliased; zeroed post-conv

    const int tid  = threadIdx.x;
    const int w    = tid >> 6;       // 0..3
    const int lane = tid & 63;
    const int l15  = lane & 15;
    const int l4   = lane >> 4;
    const int wc   = w * 64;

    const int mb  = blockIdx.x;
    const int dir = mb & 1;
    const int s   = (mb >> 1) & 63;
    const int bn  = mb >> 7;         // 0..31
    const int sg  = dir ? (63 - s) : s;

    // strat inline from cnts
    const unsigned int* cnts = (const unsigned int*)wsf + WOFF_CNT;
    const unsigned int ct = cnts[bn >> 2], cp = cnts[8 + (bn >> 2)];
    const float ratio = (cp > 0u) ? ((float)ct / (float)(cp < 1u ? 1u : cp)) : 0.0f;
    const int strat = (ratio >= 0.4f) ? 1 : 0;

    const float* b1 = dir ? b1b : b1f;
    const float* cbp = dir ? Cbb : Cbf;
    const char* w1sl = (const char*)(wsf + WOFF_W1T) + dir * 65536;
    const char* cwsl = (const char*)(wsf + WOFF_CWT) + dir * 393216;

    // ---------- stage tok f16 into hb[0..16KB), 256B rows, XOR-swizzled ----------
    {
        const int row = tid >> 2;          // 0..63  (= lp)
        const int qtr = tid & 3;           // 32-float chunk
        const int r1i = strat ? row : sg;
        const int r2i = strat ? sg : row;
        const float* src = x + (((size_t)bn * 64 + r1i) * 8192
                                + (size_t)r2i * 128 + qtr * 32);
        const int rbase = row * 256 + qtr * 64;
        const int sw = (row & 7) << 4;
        #pragma unroll
        for (int j = 0; j < 4; ++j) {
            float4 p0 = *(const float4*)(src + j * 8);
            float4 p1 = *(const float4*)(src + j * 8 + 4);
            union { pkh2 h2[2]; uint2 u; } pa, pb;
            pa.h2[0] = __builtin_amdgcn_cvt_pkrtz(p0.x, p0.y);
            pa.h2[1] = __builtin_amdgcn_cvt_pkrtz(p0.z, p0.w);
            pb.h2[0] = __builtin_amdgcn_cvt_pkrtz(p1.x, p1.y);
            pb.h2[1] = __builtin_amdgcn_cvt_pkrtz(p1.z, p1.w);
            uint4 o4 = make_uint4(pa.u.x, pa.u.y, pb.u.x, pb.u.y);
            *(uint4*)(hb + ((rbase + j * 16) ^ sw)) = o4;
        }
    }
    __syncthreads();   // tok ready

    // ---------- GEMM1 (swapped): h[l][f] = silu(tok@W1 + b1) ----------
    f32x4 acc1[4][4];
    #pragma unroll
    for (int i = 0; i < 4; ++i)
        #pragma unroll
        for (int j = 0; j < 4; ++j)
            acc1[i][j] = (f32x4){0.f, 0.f, 0.f, 0.f};

    #pragma unroll
    for (int ks = 0; ks < 4; ++ks) {
        fp16x8 wa[4];   // A = W1 frags (M = f) from L2
        #pragma unroll
        for (int mt = 0; mt < 4; ++mt)
            wa[mt] = *(const fp16x8*)(w1sl
                + (ks * 256 + wc + mt * 16 + l15) * 64 + l4 * 16);
        fp16x8 tb[4];   // B = tok frags (N = l) from LDS
        #pragma unroll
        for (int t = 0; t < 4; ++t) {
            int row = t * 16 + l15;
            int byte = (row * 256 + ks * 64 + l4 * 16) ^ ((row & 7) << 4);
            tb[t] = *(const fp16x8*)(hb + byte);
        }
        #pragma unroll
        for (int mt = 0; mt < 4; ++mt)
            #pragma unroll
            for (int t = 0; t < 4; ++t)
                acc1[mt][t] = __builtin_amdgcn_mfma_f32_16x16x32_f16(
                    wa[mt], tb[t], acc1[mt][t], 0, 0, 0);
    }

    float b1r[4][4];
    #pragma unroll
    for (int mt = 0; mt < 4; ++mt)
        #pragma unroll
        for (int q = 0; q < 4; ++q)
            b1r[mt][q] = b1[wc + mt * 16 + l4 * 4 + q];

    __syncthreads();  // all tok reads done before overwrite
    #pragma unroll
    for (int t = 0; t < 4; ++t) {
        int l = t * 16 + l15;
        int rowoff = l * 512;
        int sw = (l & 7) << 4;
        #pragma unroll
        for (int mt = 0; mt < 4; ++mt) {
            f32x4 a = acc1[mt][t];
            union { pkh2 h2[2]; uint2 u; } pk;
            pk.h2[0] = __builtin_amdgcn_cvt_pkrtz(
                silu_f(a[0] + b1r[mt][0]), silu_f(a[1] + b1r[mt][1]));
            pk.h2[1] = __builtin_amdgcn_cvt_pkrtz(
                silu_f(a[2] + b1r[mt][2]), silu_f(a[3] + b1r[mt][3]));
            int byte = (rowoff + (wc + mt * 16 + l4 * 4) * 2) ^ sw;
            *(uint2*)(hb + byte) = pk.u;
        }
    }
    __syncthreads();  // h ready

    // ---------- conv GEMM: M=64, K=768, 24 slices, depth-1 B prefetch ----------
    f32x4 acc2[4][4];
    #pragma unroll
    for (int i = 0; i < 4; ++i)
        #pragma unroll
        for (int j = 0; j < 4; ++j)
            acc2[i][j] = (f32x4){0.f, 0.f, 0.f, 0.f};

    const char* cw_w = cwsl + (size_t)(wc + l15) * 64 + l4 * 16;
    fp16x8 bq[4];
    #pragma unroll
    for (int t = 0; t < 4; ++t)
        bq[t] = *(const fp16x8*)(cw_w + t * 1024);

    for (int ks = 0; ks < 24; ++ks) {
        fp16x8 bnx[4];
        if (ks < 23) {
            #pragma unroll
            for (int t = 0; t < 4; ++t)
                bnx[t] = *(const fp16x8*)(cw_w + (ks + 1) * 16384 + t * 1024);
        }
        const int brow = l15 + (ks >> 3);
        const int base = (brow * 512 + (ks & 7) * 64 + l4 * 16)
                         ^ ((brow & 7) << 4);
        fp16x8 af[4];
        #pragma unroll
        for (int mt = 0; mt < 4; ++mt)
            af[mt] = *(const fp16x8*)(hb + base + mt * 8192);   // mt=3 tail may read
        __builtin_amdgcn_s_setprio(1);                          // OOB: rows 64/65 ->
        #pragma unroll                                          // discarded outputs
        for (int t = 0; t < 4; ++t)
            #pragma unroll
            for (int mt = 0; mt < 4; ++mt)
                acc2[mt][t] = __builtin_amdgcn_mfma_f32_16x16x32_f16(
                    af[mt], bq[t], acc2[mt][t], 0, 0, 0);
        __builtin_amdgcn_s_setprio(0);
        #pragma unroll
        for (int t = 0; t < 4; ++t) bq[t] = bnx[t];
    }

    // red aliases hb -- conv reads done; zero, then accumulate
    __syncthreads();
    if (tid < 64) red[tid] = 0.0f;
    __syncthreads();

    // epilogue: silu(conv + cb) * v, reduce over o -> red
    float cbv[4], vv[4];
    #pragma unroll
    for (int t = 0; t < 4; ++t) {
        int col = wc + t * 16 + l15;
        cbv[t] = cbp[col];
        vv[t]  = wsf[(dir ? WOFF_VB : WOFF_VF) + col];
    }
    #pragma unroll
    for (int mt = 0; mt < 4; ++mt) {
        #pragma unroll
        for (int q = 0; q < 4; ++q) {
            float v0 = 0.f;
            #pragma unroll
            for (int t = 0; t < 4; ++t)
                v0 += silu_f(acc2[mt][t][q] + cbv[t]) * vv[t];
            v0 += __shfl_xor(v0, 1);
            v0 += __shfl_xor(v0, 2);
            v0 += __shfl_xor(v0, 4);
            v0 += __shfl_xor(v0, 8);
            if (l15 == 0) atomicAdd(&red[mt * 16 + l4 * 4 + q], v0);
        }
    }

    __syncthreads();
    if (tid < 62) {
        float add = red[tid] + (dir ? 0.0f : wsf[WOFF_CONST]);
        atomicAdd(&out[((size_t)bn * 64 + s) * 62 + tid], add);
    }
}

extern "C" void kernel_launch(void* const* d_in, const int* in_sizes, int n_in,
                              void* d_out, int out_size, void* d_ws, size_t ws_size,
                              hipStream_t stream) {
    (void)in_sizes; (void)n_in; (void)ws_size;
    const float* x    = (const float*)d_in[0];
    const float* corr = (const float*)d_in[1];
    const float* W1f  = (const float*)d_in[2];
    const float* b1f  = (const float*)d_in[3];
    const float* Cwf  = (const float*)d_in[4];
    const float* Cbf  = (const float*)d_in[5];
    const float* W2f  = (const float*)d_in[6];
    const float* b2f  = (const float*)d_in[7];
    const float* W1b  = (const float*)d_in[8];
    const float* b1b  = (const float*)d_in[9];
    const float* Cwb  = (const float*)d_in[10];
    const float* Cbb  = (const float*)d_in[11];
    const float* W2b  = (const float*)d_in[12];
    const float* b2b  = (const float*)d_in[13];
    const float* Wr   = (const float*)d_in[14];
    const float* br   = (const float*)d_in[15];
    float* out = (float*)d_out;
    float* wsf = (float*)d_ws;

    hipMemsetAsync(wsf + WOFF_CNT, 0, 16 * sizeof(unsigned int), stream);
    hipMemsetAsync(out, 0, (size_t)out_size * sizeof(float), stream);
    prep_kernel<<<576, 512, 0, stream>>>(corr, W2f, b2f, W2b, b2b, Wr, br,
                                         W1f, W1b, Cwf, Cwb, wsf);
    fused_main<<<4096, 256, 0, stream>>>(x, b1f, Cbf, b1b, Cbb, wsf, out);
}

// Round 17
// 208.481 us; speedup vs baseline: 1.2450x; 1.2450x over previous
//
#include <hip/hip_runtime.h>
#include <hip/hip_bf16.h>

// ---------------- problem constants ----------------
// x: [B=8, N1=4, S=64, L=8192], PATCH=128 -> Lp=64, P=128, F=256, Lout=62
// out: [8,4,64,62,1] fp32

typedef _Float16 fp16_t;
typedef _Float16 fp16x8 __attribute__((ext_vector_type(8)));
typedef __fp16 pkh2 __attribute__((ext_vector_type(2)));   // cvt_pkrtz result type
typedef float f32x4 __attribute__((ext_vector_type(4)));

// ws float-word offsets
constexpr int WOFF_CNT   = 0;     // 16 uints
constexpr int WOFF_CONST = 32;    // 1 float
constexpr int WOFF_VF    = 64;    // 256 floats
constexpr int WOFF_VB    = 320;   // 256 floats
constexpr int WOFF_W1T   = 1024;                // f16 [2][4][256][32]
constexpr int WOFF_CWT   = WOFF_W1T + 32768;    // f16 [2][24][256][32]

constexpr int HBUF = 64 * 512;    // 32 KB per s-half

// silu via v_rcp (1 ulp): R13 PMC confirmed VALUBusy 52% -> 27% vs IEEE divide.
__device__ __forceinline__ float silu_f(float v) {
    return v * __builtin_amdgcn_rcpf(1.0f + __expf(-v));
}

// ---------------- prep (R15-verified 256-thread form) ---------------------------
// bid <512   : raw-space corr counting for (b = bid>>6, s = bid&63)
// bid 512-559: conv-weight slice pack; 560-567: W1 pack; 568-575: v = W2@Wr
__global__ __launch_bounds__(256) void prep_kernel(
    const float* __restrict__ c,
    const float* __restrict__ W2f, const float* __restrict__ b2f,
    const float* __restrict__ W2b, const float* __restrict__ b2b,
    const float* __restrict__ Wr,  const float* __restrict__ br,
    const float* __restrict__ W1f, const float* __restrict__ W1b,
    const float* __restrict__ Cwf, const float* __restrict__ Cwb,
    float* __restrict__ wsf) {
    const int bid = blockIdx.x;
    const int tid = threadIdx.x;

    if (bid < 512) {
        const int b = bid >> 6, s = bid & 63;
        unsigned int* cnts = (unsigned int*)wsf + WOFF_CNT;
        const float* cb = c + (size_t)b * 65536;

        __shared__ __align__(16) float rowv[1024];
        __shared__ float ms_sh, ss_sh;
        *(float4*)&rowv[tid * 4] = *(const float4*)&cb[s * 1024 + tid * 4];
        __syncthreads();

        const int t = tid >> 2, part = tid & 3;
        const float4* src  = (const float4*)(cb + t * 1024 + part * 256);
        const float4* mine = (const float4*)(rowv + part * 256);
        float dot = 0.0f, sum = 0.0f, sq = 0.0f;
        #pragma unroll 8
        for (int i = 0; i < 64; ++i) {
            float4 a = mine[i];
            float4 bb = src[i];
            dot += a.x * bb.x + a.y * bb.y + a.z * bb.z + a.w * bb.w;
            sum += bb.x + bb.y + bb.z + bb.w;
            sq  += bb.x * bb.x + bb.y * bb.y + bb.z * bb.z + bb.w * bb.w;
        }
        dot += __shfl_down(dot, 2); dot += __shfl_down(dot, 1);
        sum += __shfl_down(sum, 2); sum += __shfl_down(sum, 1);
        sq  += __shfl_down(sq, 2);  sq  += __shfl_down(sq, 1);

        float mt = 0.0f, st = 0.0f;
        if (part == 0) {
            mt = sum * (1.0f / 1024.0f);
            st = sqrtf(fmaxf((sq - 1024.0f * mt * mt) * (1.0f / 1023.0f), 0.0f));
            if (t == s) { ms_sh = mt; ss_sh = st; }
        }
        __syncthreads();
        const float ms = ms_sh, ss = ss_sh;

        const bool valid = (part == 0) && (t != s);
        const float ctr = dot - 1024.0f * ms * mt;               // 1024*cov
        unsigned long long mthr = __ballot(valid && (ctr > 0.6f * 1024.0f * ss * st));
        unsigned long long mpos = __ballot(valid && (ctr > 0.0f));
        if ((tid & 63) == 0) {
            atomicAdd(&cnts[b],     (unsigned int)__popcll(mthr));
            atomicAdd(&cnts[8 + b], (unsigned int)__popcll(mpos));
        }
    } else if (bid < 560) {
        const int idx = bid - 512;
        const int d = idx / 24, ks = idx % 24;
        const float* Cw = d ? Cwb : Cwf;
        fp16_t* cwt = (fp16_t*)(wsf + WOFF_CWT) + d * 196608;
        const int base = ks * 32;
        const int k = base >> 8, i0 = base & 255;
        fp16x8 v[4];
        #pragma unroll
        for (int j = 0; j < 4; ++j)
            #pragma unroll
            for (int e = 0; e < 8; ++e)
                v[j][e] = (fp16_t)Cw[(tid * 256 + i0 + j * 8 + e) * 3 + k];
        fp16x8* dst = (fp16x8*)(cwt + (ks * 256 + tid) * 32);
        dst[0] = v[0]; dst[1] = v[1]; dst[2] = v[2]; dst[3] = v[3];
    } else if (bid < 568) {
        const int sl = bid - 560;
        const int d = sl >> 2, ks = sl & 3;
        const float* W1 = d ? W1b : W1f;
        fp16_t* w1t = (fp16_t*)(wsf + WOFF_W1T) + d * 32768;
        fp16x8 v[4];
        #pragma unroll
        for (int j = 0; j < 4; ++j)
            #pragma unroll
            for (int e = 0; e < 8; ++e)
                v[j][e] = (fp16_t)W1[(ks * 32 + j * 8 + e) * 256 + tid];
        fp16x8* dst = (fp16x8*)(w1t + (ks * 256 + tid) * 32);
        dst[0] = v[0]; dst[1] = v[1]; dst[2] = v[2]; dst[3] = v[3];
    } else {
        const int vb = bid - 568;
        const int d = vb >> 2, q = vb & 3;
        const int w = tid >> 6, lane = tid & 63;
        const float* W2 = d ? W2b : W2f;
        float4 wr4 = ((const float4*)Wr)[lane];
        for (int it = 0; it < 16; ++it) {
            int row = q * 64 + w * 16 + it;
            float4 a = ((const float4*)(W2 + row * 256))[lane];
            float p = a.x * wr4.x + a.y * wr4.y + a.z * wr4.z + a.w * wr4.w;
            #pragma unroll
            for (int off = 32; off > 0; off >>= 1) p += __shfl_down(p, off);
            if (lane == 0) wsf[(d ? WOFF_VB : WOFF_VF) + row] = p;
        }
        if (bid == 568 && tid == 0) {
            float cc = 0.0f;
            for (int g = 0; g < 256; ++g) cc += (b2f[g] + b2b[g]) * Wr[g];
            wsf[WOFF_CONST] = cc + br[0];
        }
    }
}

// ---------------- fused main: (bn, sp, dir) per block, M=128, 8 waves -----------
// grid 2048: dir = mb&1, sp = (mb>>1)&31, bn = mb>>6. 512 thr; wave w owns cols
// [32w, 32w+32). Two s per block -> each weight B-frag feeds 2x M (halves L2
// weight stream, the ~53us component). Register budget: 64 AGPR (acc phases) +
// ~60 VGPR via half-split tb/af clusters -> fits 128-combined cap @4 waves/SIMD.
// LDS 66560 (2 h-buffers + 1KB OOB tail) -> 2 blocks/CU = 16 waves/CU.
// Conv tail rows 62/63 read garbage (finite f16 / uninit LDS) -> quarantined in
// red[62,63]/[126,127], never stored (R16-verified pattern).
__global__ __launch_bounds__(512, 4) void fused_main(
    const float* __restrict__ x,
    const float* __restrict__ b1f, const float* __restrict__ Cbf,
    const float* __restrict__ b1b, const float* __restrict__ Cbb,
    const float* __restrict__ wsf,
    float* __restrict__ out) {
    __shared__ __align__(16) char hb[2 * HBUF + 1024];   // 66560 B
    float* red = (float*)hb;                             // aliased post-conv

    const int tid  = threadIdx.x;
    const int w    = tid >> 6;       // 0..7
    const int lane = tid & 63;
    const int l15  = lane & 15;
    const int l4   = lane >> 4;
    const int wc   = w * 32;

    const int mb  = blockIdx.x;
    const int dir = mb & 1;
    const int sp  = (mb >> 1) & 31;
    const int bn  = mb >> 6;         // 0..31
    const int s0  = sp * 2, s1 = s0 + 1;

    // strat inline from cnts
    const unsigned int* cnts = (const unsigned int*)wsf + WOFF_CNT;
    const unsigned int ct = cnts[bn >> 2], cp = cnts[8 + (bn >> 2)];
    const float ratio = (cp > 0u) ? ((float)ct / (float)(cp < 1u ? 1u : cp)) : 0.0f;
    const int strat = (ratio >= 0.4f) ? 1 : 0;

    const float* b1 = dir ? b1b : b1f;
    const float* cbp = dir ? Cbb : Cbf;
    const char* w1sl = (const char*)(wsf + WOFF_W1T) + dir * 65536;
    const char* cwsl = (const char*)(wsf + WOFF_CWT) + dir * 393216;

    // ---------- stage tok f16 (both s) into hb, 256B rows, XOR-swizzled ----------
    {
        const int row_g = tid >> 2;        // 0..127
        const int half  = row_g >> 6;      // 0 -> s0, 1 -> s1
        const int row   = row_g & 63;      // lp
        const int qtr   = tid & 3;
        const int sv  = half ? s1 : s0;
        const int sg  = dir ? (63 - sv) : sv;
        const int r1i = strat ? row : sg;
        const int r2i = strat ? sg : row;
        const float* src = x + (((size_t)bn * 64 + r1i) * 8192
                                + (size_t)r2i * 128 + qtr * 32);
        char* hbt = hb + half * HBUF;
        const int rbase = row * 256 + qtr * 64;
        const int sw = (row & 7) << 4;
        #pragma unroll
        for (int j = 0; j < 4; ++j) {
            float4 p0 = *(const float4*)(src + j * 8);
            float4 p1 = *(const float4*)(src + j * 8 + 4);
            union { pkh2 h2[2]; uint2 u; } pa, pb;
            pa.h2[0] = __builtin_amdgcn_cvt_pkrtz(p0.x, p0.y);
            pa.h2[1] = __builtin_amdgcn_cvt_pkrtz(p0.z, p0.w);
            pb.h2[0] = __builtin_amdgcn_cvt_pkrtz(p1.x, p1.y);
            pb.h2[1] = __builtin_amdgcn_cvt_pkrtz(p1.z, p1.w);
            uint4 o4 = make_uint4(pa.u.x, pa.u.y, pb.u.x, pb.u.y);
            *(uint4*)(hbt + ((rbase + j * 16) ^ sw)) = o4;
        }
    }
    __syncthreads();   // tok ready

    // ---------- GEMM1 (swapped): h[l][f] = silu(tok@W1 + b1), both s -------------
    f32x4 acc1[2][8];
    #pragma unroll
    for (int i = 0; i < 2; ++i)
        #pragma unroll
        for (int j = 0; j < 8; ++j)
            acc1[i][j] = (f32x4){0.f, 0.f, 0.f, 0.f};

    #pragma unroll
    for (int ks = 0; ks < 4; ++ks) {
        fp16x8 wa[2];   // A = W1 frags (M = f, wave's 32 cols)
        #pragma unroll
        for (int mt = 0; mt < 2; ++mt)
            wa[mt] = *(const fp16x8*)(w1sl
                + (ks * 256 + wc + mt * 16 + l15) * 64 + l4 * 16);
        #pragma unroll
        for (int half = 0; half < 2; ++half) {   // half-split keeps tb at 4 regs
            const char* hbt = hb + half * HBUF;
            fp16x8 tb[4];
            #pragma unroll
            for (int t = 0; t < 4; ++t) {
                int row = t * 16 + l15;
                int byte = (row * 256 + ks * 64 + l4 * 16) ^ ((row & 7) << 4);
                tb[t] = *(const fp16x8*)(hbt + byte);
            }
            #pragma unroll
            for (int mt = 0; mt < 2; ++mt)
                #pragma unroll
                for (int t = 0; t < 4; ++t)
                    acc1[mt][half * 4 + t] = __builtin_amdgcn_mfma_f32_16x16x32_f16(
                        wa[mt], tb[t], acc1[mt][half * 4 + t], 0, 0, 0);
        }
    }

    float b1r[2][4];
    #pragma unroll
    for (int mt = 0; mt < 2; ++mt)
        #pragma unroll
        for (int q = 0; q < 4; ++q)
            b1r[mt][q] = b1[wc + mt * 16 + l4 * 4 + q];

    __syncthreads();  // all tok reads done before overwrite
    #pragma unroll
    for (int t = 0; t < 8; ++t) {
        char* hbt = hb + (t >> 2) * HBUF;
        int l = (t & 3) * 16 + l15;
        int rowoff = l * 512;
        int sw = (l & 7) << 4;
        #pragma unroll
        for (int mt = 0; mt < 2; ++mt) {
            f32x4 a = acc1[mt][t];
            union { pkh2 h2[2]; uint2 u; } pk;
            pk.h2[0] = __builtin_amdgcn_cvt_pkrtz(
                silu_f(a[0] + b1r[mt][0]), silu_f(a[1] + b1r[mt][1]));
            pk.h2[1] = __builtin_amdgcn_cvt_pkrtz(
                silu_f(a[2] + b1r[mt][2]), silu_f(a[3] + b1r[mt][3]));
            int byte = (rowoff + (wc + mt * 16 + l4 * 4) * 2) ^ sw;
            *(uint2*)(hbt + byte) = pk.u;
        }
    }
    __syncthreads();  // h ready

    // ---------- conv GEMM: M=128 (2 s), K=768, 24 slices, depth-1 B prefetch -----
    f32x4 acc2[8][2];
    #pragma unroll
    for (int i = 0; i < 8; ++i)
        #pragma unroll
        for (int j = 0; j < 2; ++j)
            acc2[i][j] = (f32x4){0.f, 0.f, 0.f, 0.f};

    const char* cw_w = cwsl + (size_t)(wc + l15) * 64 + l4 * 16;
    fp16x8 bq[2];
    #pragma unroll
    for (int t = 0; t < 2; ++t)
        bq[t] = *(const fp16x8*)(cw_w + t * 1024);

    for (int ks = 0; ks < 24; ++ks) {
        fp16x8 bnx[2];
        if (ks < 23) {
            #pragma unroll
            for (int t = 0; t < 2; ++t)
                bnx[t] = *(const fp16x8*)(cw_w + (ks + 1) * 16384 + t * 1024);
        }
        const int brow = l15 + (ks >> 3);
        const int base = (brow * 512 + (ks & 7) * 64 + l4 * 16)
                         ^ ((brow & 7) << 4);
        #pragma unroll
        for (int half = 0; half < 2; ++half) {   // half-split keeps af at 4 regs
            const char* hbt = hb + half * HBUF;
            fp16x8 af[4];
            #pragma unroll
            for (int mt = 0; mt < 4; ++mt)
                af[mt] = *(const fp16x8*)(hbt + base + mt * 8192);
            __builtin_amdgcn_s_setprio(1);
            #pragma unroll
            for (int t = 0; t < 2; ++t)
                #pragma unroll
                for (int mt = 0; mt < 4; ++mt)
                    acc2[half * 4 + mt][t] = __builtin_amdgcn_mfma_f32_16x16x32_f16(
                        af[mt], bq[t], acc2[half * 4 + mt][t], 0, 0, 0);
            __builtin_amdgcn_s_setprio(0);
        }
        #pragma unroll
        for (int t = 0; t < 2; ++t) bq[t] = bnx[t];
    }

    // red aliases hb -- conv reads done; zero, then accumulate
    __syncthreads();
    if (tid < 128) red[tid] = 0.0f;
    __syncthreads();

    // epilogue: silu(conv + cb) * v, reduce over o -> red
    float cbv[2], vv[2];
    #pragma unroll
    for (int t = 0; t < 2; ++t) {
        int col = wc + t * 16 + l15;
        cbv[t] = cbp[col];
        vv[t]  = wsf[(dir ? WOFF_VB : WOFF_VF) + col];
    }
    #pragma unroll
    for (int mt = 0; mt < 8; ++mt) {
        #pragma unroll
        for (int q = 0; q < 4; ++q) {
            float v0 = 0.f;
            #pragma unroll
            for (int t = 0; t < 2; ++t)
                v0 += silu_f(acc2[mt][t][q] + cbv[t]) * vv[t];
            v0 += __shfl_xor(v0, 1);
            v0 += __shfl_xor(v0, 2);
            v0 += __shfl_xor(v0, 4);
            v0 += __shfl_xor(v0, 8);
            if (l15 == 0) {
                int idx = (mt >> 2) * 64 + (mt & 3) * 16 + l4 * 4 + q;
                atomicAdd(&red[idx], v0);
            }
        }
    }

    __syncthreads();
    const float constv = dir ? 0.0f : wsf[WOFF_CONST];
    if (tid < 62)
        atomicAdd(&out[((size_t)bn * 64 + s0) * 62 + tid], red[tid] + constv);
    else if (tid >= 64 && tid < 126)
        atomicAdd(&out[((size_t)bn * 64 + s1) * 62 + (tid - 64)], red[tid] + constv);
}

extern "C" void kernel_launch(void* const* d_in, const int* in_sizes, int n_in,
                              void* d_out, int out_size, void* d_ws, size_t ws_size,
                              hipStream_t stream) {
    (void)in_sizes; (void)n_in; (void)ws_size;
    const float* x    = (const float*)d_in[0];
    const float* corr = (const float*)d_in[1];
    const float* W1f  = (const float*)d_in[2];
    const float* b1f  = (const float*)d_in[3];
    const float* Cwf  = (const float*)d_in[4];
    const float* Cbf  = (const float*)d_in[5];
    const float* W2f  = (const float*)d_in[6];
    const float* b2f  = (const float*)d_in[7];
    const float* W1b  = (const float*)d_in[8];
    const float* b1b  = (const float*)d_in[9];
    const float* Cwb  = (const float*)d_in[10];
    const float* Cbb  = (const float*)d_in[11];
    const float* W2b  = (const float*)d_in[12];
    const float* b2b  = (const float*)d_in[13];
    const float* Wr   = (const float*)d_in[14];
    const float* br   = (const float*)d_in[15];
    float* out = (float*)d_out;
    float* wsf = (float*)d_ws;

    hipMemsetAsync(wsf + WOFF_CNT, 0, 16 * sizeof(unsigned int), stream);
    hipMemsetAsync(out, 0, (size_t)out_size * sizeof(float), stream);
    prep_kernel<<<576, 256, 0, stream>>>(corr, W2f, b2f, W2b, b2b, Wr, br,
                                         W1f, W1b, Cwf, Cwb, wsf);
    fused_main<<<2048, 512, 0, stream>>>(x, b1f, Cbf, b1b, Cbb, wsf, out);
}

// Round 18
// 160.550 us; speedup vs baseline: 1.6167x; 1.2985x over previous
//
#include <hip/hip_runtime.h>
#include <hip/hip_bf16.h>

// ---------------- problem constants ----------------
// x: [B=8, N1=4, S=64, L=8192], PATCH=128 -> Lp=64, P=128, F=256, Lout=62
// out: [8,4,64,62,1] fp32

typedef _Float16 fp16_t;
typedef _Float16 fp16x8 __attribute__((ext_vector_type(8)));
typedef __fp16 pkh2 __attribute__((ext_vector_type(2)));   // cvt_pkrtz result type
typedef float f32x4 __attribute__((ext_vector_type(4)));

// ws float-word offsets
constexpr int WOFF_CONST = 32;    // 1 float
constexpr int WOFF_VF    = 64;    // 256 floats
constexpr int WOFF_VB    = 320;   // 256 floats
constexpr int WOFF_W1T   = 1024;                // f16 [2][4][256][32]
constexpr int WOFF_CWT   = WOFF_W1T + 32768;    // f16 [2][24][256][32] = 196608 words
constexpr int WOFF_CTHR  = WOFF_CWT + 196608;   // 512 uints, per-(b,s) cnt_thr
constexpr int WOFF_CPOS  = WOFF_CTHR + 512;     // 512 uints, per-(b,s) cnt_pos

constexpr int HBUF = 64 * 512;    // 32 KB per s-half

// silu via v_rcp (1 ulp): R13 PMC confirmed VALUBusy 52% -> 27% vs IEEE divide.
__device__ __forceinline__ float silu_f(float v) {
    return v * __builtin_amdgcn_rcpf(1.0f + __expf(-v));
}

// ---------------- prep (256 thr): rowcount + weight pack ------------------------
// bid <512   : raw-space corr counting for (b = bid>>6, s = bid&63);
//              writes per-(b,s) counts NON-atomically (no memset needed).
// bid 512-559: conv-weight slice pack; 560-567: W1 pack; 568-575: v = W2@Wr
__global__ __launch_bounds__(256) void prep_kernel(
    const float* __restrict__ c,
    const float* __restrict__ W2f, const float* __restrict__ b2f,
    const float* __restrict__ W2b, const float* __restrict__ b2b,
    const float* __restrict__ Wr,  const float* __restrict__ br,
    const float* __restrict__ W1f, const float* __restrict__ W1b,
    const float* __restrict__ Cwf, const float* __restrict__ Cwb,
    float* __restrict__ wsf) {
    const int bid = blockIdx.x;
    const int tid = threadIdx.x;

    if (bid < 512) {
        const int b = bid >> 6, s = bid & 63;
        const float* cb = c + (size_t)b * 65536;

        __shared__ __align__(16) float rowv[1024];
        __shared__ float ms_sh, ss_sh;
        __shared__ unsigned int ls[8];
        *(float4*)&rowv[tid * 4] = *(const float4*)&cb[s * 1024 + tid * 4];
        __syncthreads();

        const int t = tid >> 2, part = tid & 3;
        const float4* src  = (const float4*)(cb + t * 1024 + part * 256);
        const float4* mine = (const float4*)(rowv + part * 256);
        float dot = 0.0f, sum = 0.0f, sq = 0.0f;
        #pragma unroll 8
        for (int i = 0; i < 64; ++i) {
            float4 a = mine[i];
            float4 bb = src[i];
            dot += a.x * bb.x + a.y * bb.y + a.z * bb.z + a.w * bb.w;
            sum += bb.x + bb.y + bb.z + bb.w;
            sq  += bb.x * bb.x + bb.y * bb.y + bb.z * bb.z + bb.w * bb.w;
        }
        dot += __shfl_down(dot, 2); dot += __shfl_down(dot, 1);
        sum += __shfl_down(sum, 2); sum += __shfl_down(sum, 1);
        sq  += __shfl_down(sq, 2);  sq  += __shfl_down(sq, 1);

        float mt = 0.0f, st = 0.0f;
        if (part == 0) {
            mt = sum * (1.0f / 1024.0f);
            st = sqrtf(fmaxf((sq - 1024.0f * mt * mt) * (1.0f / 1023.0f), 0.0f));
            if (t == s) { ms_sh = mt; ss_sh = st; }
        }
        __syncthreads();
        const float ms = ms_sh, ss = ss_sh;

        const bool valid = (part == 0) && (t != s);
        const float ctr = dot - 1024.0f * ms * mt;               // 1024*cov
        unsigned long long mthr = __ballot(valid && (ctr > 0.6f * 1024.0f * ss * st));
        unsigned long long mpos = __ballot(valid && (ctr > 0.0f));
        const int w = tid >> 6;
        if ((tid & 63) == 0) {
            ls[w]     = (unsigned int)__popcll(mthr);
            ls[4 + w] = (unsigned int)__popcll(mpos);
        }
        __syncthreads();
        if (tid == 0) {
            unsigned int* cthr = (unsigned int*)wsf + WOFF_CTHR;
            unsigned int* cpos = (unsigned int*)wsf + WOFF_CPOS;
            cthr[bid] = ls[0] + ls[1] + ls[2] + ls[3];
            cpos[bid] = ls[4] + ls[5] + ls[6] + ls[7];
        }
    } else if (bid < 560) {
        const int idx = bid - 512;
        const int d = idx / 24, ks = idx % 24;
        const float* Cw = d ? Cwb : Cwf;
        fp16_t* cwt = (fp16_t*)(wsf + WOFF_CWT) + d * 196608;
        const int base = ks * 32;
        const int k = base >> 8, i0 = base & 255;
        fp16x8 v[4];
        #pragma unroll
        for (int j = 0; j < 4; ++j)
            #pragma unroll
            for (int e = 0; e < 8; ++e)
                v[j][e] = (fp16_t)Cw[(tid * 256 + i0 + j * 8 + e) * 3 + k];
        fp16x8* dst = (fp16x8*)(cwt + (ks * 256 + tid) * 32);
        dst[0] = v[0]; dst[1] = v[1]; dst[2] = v[2]; dst[3] = v[3];
    } else if (bid < 568) {
        const int sl = bid - 560;
        const int d = sl >> 2, ks = sl & 3;
        const float* W1 = d ? W1b : W1f;
        fp16_t* w1t = (fp16_t*)(wsf + WOFF_W1T) + d * 32768;
        fp16x8 v[4];
        #pragma unroll
        for (int j = 0; j < 4; ++j)
            #pragma unroll
            for (int e = 0; e < 8; ++e)
                v[j][e] = (fp16_t)W1[(ks * 32 + j * 8 + e) * 256 + tid];
        fp16x8* dst = (fp16x8*)(w1t + (ks * 256 + tid) * 32);
        dst[0] = v[0]; dst[1] = v[1]; dst[2] = v[2]; dst[3] = v[3];
    } else {
        const int vb = bid - 568;
        const int d = vb >> 2, q = vb & 3;
        const int w = tid >> 6, lane = tid & 63;
        const float* W2 = d ? W2b : W2f;
        float4 wr4 = ((const float4*)Wr)[lane];
        for (int it = 0; it < 16; ++it) {
            int row = q * 64 + w * 16 + it;
            float4 a = ((const float4*)(W2 + row * 256))[lane];
            float p = a.x * wr4.x + a.y * wr4.y + a.z * wr4.z + a.w * wr4.w;
            #pragma unroll
            for (int off = 32; off > 0; off >>= 1) p += __shfl_down(p, off);
            if (lane == 0) wsf[(d ? WOFF_VB : WOFF_VF) + row] = p;
        }
        if (bid == 568) {
            // const term, parallel over 256 threads (was a serial tid-0 loop)
            __shared__ float cs[4];
            float p = (b2f[tid] + b2b[tid]) * Wr[tid];
            #pragma unroll
            for (int off = 32; off > 0; off >>= 1) p += __shfl_down(p, off);
            if ((tid & 63) == 0) cs[tid >> 6] = p;
            __syncthreads();
            if (tid == 0) wsf[WOFF_CONST] = cs[0] + cs[1] + cs[2] + cs[3] + br[0];
        }
    }
}

// ---------------- fused main: (bn, sp, dir) per block, M=128, 8 waves -----------
// (R17-verified core; only the strat prologue changed: wave-0 sums per-s counts.)
__global__ __launch_bounds__(512, 4) void fused_main(
    const float* __restrict__ x,
    const float* __restrict__ b1f, const float* __restrict__ Cbf,
    const float* __restrict__ b1b, const float* __restrict__ Cbb,
    const float* __restrict__ wsf,
    float* __restrict__ out) {
    __shared__ __align__(16) char hb[2 * HBUF + 1024];   // 66560 B
    __shared__ float strat_sh;
    float* red = (float*)hb;                             // aliased post-conv

    const int tid  = threadIdx.x;
    const int w    = tid >> 6;       // 0..7
    const int lane = tid & 63;
    const int l15  = lane & 15;
    const int l4   = lane >> 4;
    const int wc   = w * 32;

    const int mb  = blockIdx.x;
    const int dir = mb & 1;
    const int sp  = (mb >> 1) & 31;
    const int bn  = mb >> 6;         // 0..31
    const int s0  = sp * 2, s1 = s0 + 1;

    // strat: wave 0 sums this b's 64 per-s count pairs
    if (tid < 64) {
        const unsigned int* cthr = (const unsigned int*)wsf + WOFF_CTHR;
        const unsigned int* cpos = (const unsigned int*)wsf + WOFF_CPOS;
        unsigned int ct = cthr[(bn >> 2) * 64 + tid];
        unsigned int cp = cpos[(bn >> 2) * 64 + tid];
        #pragma unroll
        for (int off = 32; off > 0; off >>= 1) {
            ct += __shfl_down(ct, off);
            cp += __shfl_down(cp, off);
        }
        if (tid == 0) {
            float ratio = (cp > 0u) ? ((float)ct / (float)(cp < 1u ? 1u : cp)) : 0.0f;
            strat_sh = (ratio >= 0.4f) ? 1.0f : 0.0f;
        }
    }
    __syncthreads();
    const int strat = (strat_sh != 0.0f) ? 1 : 0;

    const float* b1 = dir ? b1b : b1f;
    const float* cbp = dir ? Cbb : Cbf;
    const char* w1sl = (const char*)(wsf + WOFF_W1T) + dir * 65536;
    const char* cwsl = (const char*)(wsf + WOFF_CWT) + dir * 393216;

    // ---------- stage tok f16 (both s) into hb, 256B rows, XOR-swizzled ----------
    {
        const int row_g = tid >> 2;        // 0..127
        const int half  = row_g >> 6;      // 0 -> s0, 1 -> s1
        const int row   = row_g & 63;      // lp
        const int qtr   = tid & 3;
        const int sv  = half ? s1 : s0;
        const int sg  = dir ? (63 - sv) : sv;
        const int r1i = strat ? row : sg;
        const int r2i = strat ? sg : row;
        const float* src = x + (((size_t)bn * 64 + r1i) * 8192
                                + (size_t)r2i * 128 + qtr * 32);
        char* hbt = hb + half * HBUF;
        const int rbase = row * 256 + qtr * 64;
        const int sw = (row & 7) << 4;
        #pragma unroll
        for (int j = 0; j < 4; ++j) {
            float4 p0 = *(const float4*)(src + j * 8);
            float4 p1 = *(const float4*)(src + j * 8 + 4);
            union { pkh2 h2[2]; uint2 u; } pa, pb;
            pa.h2[0] = __builtin_amdgcn_cvt_pkrtz(p0.x, p0.y);
            pa.h2[1] = __builtin_amdgcn_cvt_pkrtz(p0.z, p0.w);
            pb.h2[0] = __builtin_amdgcn_cvt_pkrtz(p1.x, p1.y);
            pb.h2[1] = __builtin_amdgcn_cvt_pkrtz(p1.z, p1.w);
            uint4 o4 = make_uint4(pa.u.x, pa.u.y, pb.u.x, pb.u.y);
            *(uint4*)(hbt + ((rbase + j * 16) ^ sw)) = o4;
        }
    }
    __syncthreads();   // tok ready

    // ---------- GEMM1 (swapped): h[l][f] = silu(tok@W1 + b1), both s -------------
    f32x4 acc1[2][8];
    #pragma unroll
    for (int i = 0; i < 2; ++i)
        #pragma unroll
        for (int j = 0; j < 8; ++j)
            acc1[i][j] = (f32x4){0.f, 0.f, 0.f, 0.f};

    #pragma unroll
    for (int ks = 0; ks < 4; ++ks) {
        fp16x8 wa[2];   // A = W1 frags (M = f, wave's 32 cols)
        #pragma unroll
        for (int mt = 0; mt < 2; ++mt)
            wa[mt] = *(const fp16x8*)(w1sl
                + (ks * 256 + wc + mt * 16 + l15) * 64 + l4 * 16);
        #pragma unroll
        for (int half = 0; half < 2; ++half) {   // half-split keeps tb at 4 regs
            const char* hbt = hb + half * HBUF;
            fp16x8 tb[4];
            #pragma unroll
            for (int t = 0; t < 4; ++t) {
                int row = t * 16 + l15;
                int byte = (row * 256 + ks * 64 + l4 * 16) ^ ((row & 7) << 4);
                tb[t] = *(const fp16x8*)(hbt + byte);
            }
            #pragma unroll
            for (int mt = 0; mt < 2; ++mt)
                #pragma unroll
                for (int t = 0; t < 4; ++t)
                    acc1[mt][half * 4 + t] = __builtin_amdgcn_mfma_f32_16x16x32_f16(
                        wa[mt], tb[t], acc1[mt][half * 4 + t], 0, 0, 0);
        }
    }

    float b1r[2][4];
    #pragma unroll
    for (int mt = 0; mt < 2; ++mt)
        #pragma unroll
        for (int q = 0; q < 4; ++q)
            b1r[mt][q] = b1[wc + mt * 16 + l4 * 4 + q];

    __syncthreads();  // all tok reads done before overwrite
    #pragma unroll
    for (int t = 0; t < 8; ++t) {
        char* hbt = hb + (t >> 2) * HBUF;
        int l = (t & 3) * 16 + l15;
        int rowoff = l * 512;
        int sw = (l & 7) << 4;
        #pragma unroll
        for (int mt = 0; mt < 2; ++mt) {
            f32x4 a = acc1[mt][t];
            union { pkh2 h2[2]; uint2 u; } pk;
            pk.h2[0] = __builtin_amdgcn_cvt_pkrtz(
                silu_f(a[0] + b1r[mt][0]), silu_f(a[1] + b1r[mt][1]));
            pk.h2[1] = __builtin_amdgcn_cvt_pkrtz(
                silu_f(a[2] + b1r[mt][2]), silu_f(a[3] + b1r[mt][3]));
            int byte = (rowoff + (wc + mt * 16 + l4 * 4) * 2) ^ sw;
            *(uint2*)(hbt + byte) = pk.u;
        }
    }
    __syncthreads();  // h ready

    // ---------- conv GEMM: M=128 (2 s), K=768, 24 slices, depth-1 B prefetch -----
    f32x4 acc2[8][2];
    #pragma unroll
    for (int i = 0; i < 8; ++i)
        #pragma unroll
        for (int j = 0; j < 2; ++j)
            acc2[i][j] = (f32x4){0.f, 0.f, 0.f, 0.f};

    const char* cw_w = cwsl + (size_t)(wc + l15) * 64 + l4 * 16;
    fp16x8 bq[2];
    #pragma unroll
    for (int t = 0; t < 2; ++t)
        bq[t] = *(const fp16x8*)(cw_w + t * 1024);

    for (int ks = 0; ks < 24; ++ks) {
        fp16x8 bnx[2];
        if (ks < 23) {
            #pragma unroll
            for (int t = 0; t < 2; ++t)
                bnx[t] = *(const fp16x8*)(cw_w + (ks + 1) * 16384 + t * 1024);
        }
        const int brow = l15 + (ks >> 3);
        const int base = (brow * 512 + (ks & 7) * 64 + l4 * 16)
                         ^ ((brow & 7) << 4);
        #pragma unroll
        for (int half = 0; half < 2; ++half) {   // half-split keeps af at 4 regs
            const char* hbt = hb + half * HBUF;
            fp16x8 af[4];
            #pragma unroll
            for (int mt = 0; mt < 4; ++mt)
                af[mt] = *(const fp16x8*)(hbt + base + mt * 8192);
            __builtin_amdgcn_s_setprio(1);
            #pragma unroll
            for (int t = 0; t < 2; ++t)
                #pragma unroll
                for (int mt = 0; mt < 4; ++mt)
                    acc2[half * 4 + mt][t] = __builtin_amdgcn_mfma_f32_16x16x32_f16(
                        af[mt], bq[t], acc2[half * 4 + mt][t], 0, 0, 0);
            __builtin_amdgcn_s_setprio(0);
        }
        #pragma unroll
        for (int t = 0; t < 2; ++t) bq[t] = bnx[t];
    }

    // red aliases hb -- conv reads done; zero, then accumulate
    __syncthreads();
    if (tid < 128) red[tid] = 0.0f;
    __syncthreads();

    // epilogue: silu(conv + cb) * v, reduce over o -> red
    float cbv[2], vv[2];
    #pragma unroll
    for (int t = 0; t < 2; ++t) {
        int col = wc + t * 16 + l15;
        cbv[t] = cbp[col];
        vv[t]  = wsf[(dir ? WOFF_VB : WOFF_VF) + col];
    }
    #pragma unroll
    for (int mt = 0; mt < 8; ++mt) {
        #pragma unroll
        for (int q = 0; q < 4; ++q) {
            float v0 = 0.f;
            #pragma unroll
            for (int t = 0; t < 2; ++t)
                v0 += silu_f(acc2[mt][t][q] + cbv[t]) * vv[t];
            v0 += __shfl_xor(v0, 1);
            v0 += __shfl_xor(v0, 2);
            v0 += __shfl_xor(v0, 4);
            v0 += __shfl_xor(v0, 8);
            if (l15 == 0) {
                int idx = (mt >> 2) * 64 + (mt & 3) * 16 + l4 * 4 + q;
                atomicAdd(&red[idx], v0);
            }
        }
    }

    __syncthreads();
    const float constv = dir ? 0.0f : wsf[WOFF_CONST];
    if (tid < 62)
        atomicAdd(&out[((size_t)bn * 64 + s0) * 62 + tid], red[tid] + constv);
    else if (tid >= 64 && tid < 126)
        atomicAdd(&out[((size_t)bn * 64 + s1) * 62 + (tid - 64)], red[tid] + constv);
}

extern "C" void kernel_launch(void* const* d_in, const int* in_sizes, int n_in,
                              void* d_out, int out_size, void* d_ws, size_t ws_size,
                              hipStream_t stream) {
    (void)in_sizes; (void)n_in; (void)ws_size;
    const float* x    = (const float*)d_in[0];
    const float* corr = (const float*)d_in[1];
    const float* W1f  = (const float*)d_in[2];
    const float* b1f  = (const float*)d_in[3];
    const float* Cwf  = (const float*)d_in[4];
    const float* Cbf  = (const float*)d_in[5];
    const float* W2f  = (const float*)d_in[6];
    const float* b2f  = (const float*)d_in[7];
    const float* W1b  = (const float*)d_in[8];
    const float* b1b  = (const float*)d_in[9];
    const float* Cwb  = (const float*)d_in[10];
    const float* Cbb  = (const float*)d_in[11];
    const float* W2b  = (const float*)d_in[12];
    const float* b2b  = (const float*)d_in[13];
    const float* Wr   = (const float*)d_in[14];
    const float* br   = (const float*)d_in[15];
    float* out = (float*)d_out;
    float* wsf = (float*)d_ws;

    hipMemsetAsync(out, 0, (size_t)out_size * sizeof(float), stream);
    prep_kernel<<<576, 256, 0, stream>>>(corr, W2f, b2f, W2b, b2b, Wr, br,
                                         W1f, W1b, Cwf, Cwb, wsf);
    fused_main<<<2048, 512, 0, stream>>>(x, b1f, Cbf, b1b, Cbb, wsf, out);
}